// Round 1
// baseline (183.604 us; speedup 1.0000x reference)
//
#include <hip/hip_runtime.h>

typedef __bf16 bf16x8 __attribute__((ext_vector_type(8)));
typedef __bf16 bf16x4 __attribute__((ext_vector_type(4)));
typedef float f32x4 __attribute__((ext_vector_type(4)));

#define MFMA_16x16x32(a, b, c) __builtin_amdgcn_mfma_f32_16x16x32_bf16((a), (b), (c), 0, 0, 0)

// XOR swizzle for tiles with 128-byte rows (64 bf16/row): permute 16B chunks
// within a row by row&7 to avoid bank conflicts on ds_read_b128 (guide §6 G4).
__device__ __forceinline__ int swz(int row, int colb) {
    return row * 128 + (colb ^ ((row & 7) << 4));
}

// ---------------- f32 -> bf16 conversion ----------------
__global__ __launch_bounds__(256) void cvt_f32_bf16(const float* __restrict__ in,
                                                    __bf16* __restrict__ out, int n4) {
    int i = blockIdx.x * 256 + threadIdx.x;
    if (i >= n4) return;
    float4 v = ((const float4*)in)[i];
    bf16x4 o;
    o[0] = (__bf16)v.x; o[1] = (__bf16)v.y; o[2] = (__bf16)v.z; o[3] = (__bf16)v.w;
    ((bf16x4*)out)[i] = o;
}

// ---- GEMM body: C[M][N] = (A[M][K] * Bw[N][K]^T + bias[N]) * scale ----
// 128x128 tile, BK=64, 256 threads = 4 waves in 2x2, each wave 64x64 (4x4 frags)
template <typename OT>
__device__ __forceinline__ void gemm_body(const __bf16* __restrict__ A,
                                          const __bf16* __restrict__ Bw,
                                          const float* __restrict__ bias,
                                          OT* __restrict__ C,
                                          int M, int N, int K, float scale) {
    const int m0 = blockIdx.x * 128;
    const int n0 = blockIdx.y * 128;
    const int tid = threadIdx.x;
    const int l = tid & 63, w = tid >> 6;
    const int wr = w >> 1, wc = w & 1;
    const int lr = l & 15;
    const int lkb = (l >> 4) << 4;  // byte offset of this lane's 8-elem k-slice

    __shared__ __bf16 As[128 * 64];
    __shared__ __bf16 Bs[128 * 64];
    char* AsC = (char*)As;
    char* BsC = (char*)Bs;

    f32x4 acc[4][4] = {};

    for (int k0 = 0; k0 < K; k0 += 64) {
        __syncthreads();
#pragma unroll
        for (int r = 0; r < 4; ++r) {
            int g = r * 256 + tid;
            int row = g >> 3, c = g & 7;
            int4 va = *(const int4*)(A + (size_t)(m0 + row) * K + k0 + c * 8);
            *(int4*)(AsC + swz(row, c * 16)) = va;
            int4 vb = *(const int4*)(Bw + (size_t)(n0 + row) * K + k0 + c * 8);
            *(int4*)(BsC + swz(row, c * 16)) = vb;
        }
        __syncthreads();
#pragma unroll
        for (int kk = 0; kk < 2; ++kk) {
            bf16x8 af[4], bfr[4];
#pragma unroll
            for (int mi = 0; mi < 4; ++mi)
                af[mi] = *(const bf16x8*)(AsC + swz(wr * 64 + mi * 16 + lr, kk * 64 + lkb));
#pragma unroll
            for (int ni = 0; ni < 4; ++ni)
                bfr[ni] = *(const bf16x8*)(BsC + swz(wc * 64 + ni * 16 + lr, kk * 64 + lkb));
#pragma unroll
            for (int mi = 0; mi < 4; ++mi)
#pragma unroll
                for (int ni = 0; ni < 4; ++ni)
                    acc[mi][ni] = MFMA_16x16x32(af[mi], bfr[ni], acc[mi][ni]);
        }
    }

    // epilogue: C/D layout col = lane&15, row = (lane>>4)*4 + j
    const int rb = (l >> 4) * 4;
#pragma unroll
    for (int mi = 0; mi < 4; ++mi) {
#pragma unroll
        for (int ni = 0; ni < 4; ++ni) {
            int gn = n0 + wc * 64 + ni * 16 + lr;
            int gm = m0 + wr * 64 + mi * 16 + rb;
            float bv = bias[gn];
#pragma unroll
            for (int j = 0; j < 4; ++j) {
                float v = (acc[mi][ni][j] + bv) * scale;
                C[(size_t)(gm + j) * N + gn] = (OT)v;
            }
        }
    }
}

// QKV: one launch, grid.z selects which projection (better occupancy than 3x256 blocks)
__global__ __launch_bounds__(256) void qkv_gemm(const __bf16* __restrict__ X,
                                                const __bf16* __restrict__ Wq,
                                                const __bf16* __restrict__ Wk,
                                                const __bf16* __restrict__ Wv,
                                                const float* __restrict__ bq,
                                                const float* __restrict__ bk,
                                                const float* __restrict__ bv,
                                                __bf16* __restrict__ Qo,
                                                __bf16* __restrict__ Ko,
                                                __bf16* __restrict__ Vo) {
    int z = blockIdx.z;
    const __bf16* W = (z == 0) ? Wq : (z == 1) ? Wk : Wv;
    const float* bb = (z == 0) ? bq : (z == 1) ? bk : bv;
    __bf16* O = (z == 0) ? Qo : (z == 1) ? Ko : Vo;
    // fold 1/sqrt(d_k)=0.125 into Q (bias included): exact power-of-2 scale in bf16
    gemm_body<__bf16>(X, W, bb, O, 8192, 512, 512, (z == 0) ? 0.125f : 1.0f);
}

__global__ __launch_bounds__(256) void out_gemm(const __bf16* __restrict__ A,
                                                const __bf16* __restrict__ W,
                                                const float* __restrict__ bias,
                                                float* __restrict__ C) {
    gemm_body<float>(A, W, bias, C, 8192, 512, 512, 1.0f);
}

// ---------------- flash attention forward ----------------
// grid (T/64, H, B), 256 threads = 4 waves; wave w owns q rows [qt0+16w, qt0+16w+16)
__global__ __launch_bounds__(256) void attn_fwd(const __bf16* __restrict__ Q,
                                                const __bf16* __restrict__ K,
                                                const __bf16* __restrict__ V,
                                                __bf16* __restrict__ O) {
    const int T = 2048, Cm = 512, DK = 64;
    const int qt0 = blockIdx.x * 64;
    const int h = blockIdx.y, b = blockIdx.z;
    const int tid = threadIdx.x;
    const int l = tid & 63, w = tid >> 6;
    const int lr = l & 15;
    const int lkb = (l >> 4) << 4;

    const size_t base = ((size_t)b * T) * Cm + h * DK;

    __shared__ __bf16 Ks[64 * 64];     // K tile  [k_row][d], swizzled
    __shared__ __bf16 Vt[64 * 64];     // V tile transposed [d][k], swizzled
    __shared__ __bf16 Ps[4][16 * 64];  // per-wave P [q][k], swizzled
    char* KsC = (char*)Ks;
    char* VtC = (char*)Vt;
    char* PsC = (char*)&Ps[w][0];

    // Q fragments in registers (A-frag: row = lane&15, k = (lane>>4)*8 + j)
    bf16x8 qa[2];
    {
        const __bf16* qp = Q + base + (size_t)(qt0 + w * 16 + lr) * Cm + ((l >> 4) * 8);
        qa[0] = *(const bf16x8*)(qp);
        qa[1] = *(const bf16x8*)(qp + 32);
    }

    f32x4 o_acc[4] = {};
    float m_r[4], l_r[4];
#pragma unroll
    for (int j = 0; j < 4; ++j) { m_r[j] = -1e30f; l_r[j] = 0.f; }

    for (int kt = 0; kt < T; kt += 64) {
        __syncthreads();  // previous PV done -> Ks/Vt reusable
        // stage K tile [64][64]
#pragma unroll
        for (int r = 0; r < 2; ++r) {
            int g = r * 256 + tid;
            int row = g >> 3, c = g & 7;
            int4 vv = *(const int4*)(K + base + (size_t)(kt + row) * Cm + c * 8);
            *(int4*)(KsC + swz(row, c * 16)) = vv;
        }
        // stage V transposed: Vt[d][k]
        {
            int kc = tid >> 2, d0 = (tid & 3) * 16;
            const __bf16* vp = V + base + (size_t)(kt + kc) * Cm + d0;
            bf16x8 v0 = *(const bf16x8*)(vp);
            bf16x8 v1 = *(const bf16x8*)(vp + 8);
#pragma unroll
            for (int j = 0; j < 8; ++j) {
                *(__bf16*)(VtC + swz(d0 + j, kc * 2)) = v0[j];
                *(__bf16*)(VtC + swz(d0 + 8 + j, kc * 2)) = v1[j];
            }
        }
        __syncthreads();

        // S = Q * K^T : per-wave 16 q-rows x 64 k-cols
        f32x4 s[4] = {};
#pragma unroll
        for (int kk = 0; kk < 2; ++kk) {
#pragma unroll
            for (int ni = 0; ni < 4; ++ni) {
                bf16x8 kb = *(const bf16x8*)(KsC + swz(ni * 16 + lr, kk * 64 + lkb));
                s[ni] = MFMA_16x16x32(qa[kk], kb, s[ni]);
            }
        }

        // online softmax: lane holds rows (l>>4)*4+j, col ni*16+(l&15)
        float mx[4];
#pragma unroll
        for (int j = 0; j < 4; ++j)
            mx[j] = fmaxf(fmaxf(s[0][j], s[1][j]), fmaxf(s[2][j], s[3][j]));
#pragma unroll
        for (int msk = 1; msk < 16; msk <<= 1)
#pragma unroll
            for (int j = 0; j < 4; ++j)
                mx[j] = fmaxf(mx[j], __shfl_xor(mx[j], msk));
        float al[4], rs[4];
#pragma unroll
        for (int j = 0; j < 4; ++j) {
            float mn = fmaxf(m_r[j], mx[j]);
            al[j] = __expf(m_r[j] - mn);
            m_r[j] = mn;
            rs[j] = 0.f;
        }
#pragma unroll
        for (int ni = 0; ni < 4; ++ni) {
#pragma unroll
            for (int j = 0; j < 4; ++j) {
                float pv = __expf(s[ni][j] - m_r[j]);
                __bf16 pb = (__bf16)pv;
                rs[j] += (float)pb;  // sum the rounded value PV will actually use
                *(__bf16*)(PsC + swz((l >> 4) * 4 + j, (ni * 16 + lr) * 2)) = pb;
            }
        }
#pragma unroll
        for (int msk = 1; msk < 16; msk <<= 1)
#pragma unroll
            for (int j = 0; j < 4; ++j)
                rs[j] += __shfl_xor(rs[j], msk);
#pragma unroll
        for (int j = 0; j < 4; ++j)
            l_r[j] = l_r[j] * al[j] + rs[j];
#pragma unroll
        for (int di = 0; di < 4; ++di)
#pragma unroll
            for (int j = 0; j < 4; ++j)
                o_acc[di][j] *= al[j];
        __syncthreads();  // P visible (cross-lane), Vt stable

        // O += P * V  (A = Ps[16][64], B-frag from Vt[d][k] rows)
#pragma unroll
        for (int kk = 0; kk < 2; ++kk) {
            bf16x8 pa = *(const bf16x8*)(PsC + swz(lr, kk * 64 + lkb));
#pragma unroll
            for (int di = 0; di < 4; ++di) {
                bf16x8 vb = *(const bf16x8*)(VtC + swz(di * 16 + lr, kk * 64 + lkb));
                o_acc[di] = MFMA_16x16x32(pa, vb, o_acc[di]);
            }
        }
    }

    // epilogue: normalize and store bf16 attn output [B*T][512]
#pragma unroll
    for (int j = 0; j < 4; ++j) l_r[j] = 1.f / l_r[j];
    const int rb = (l >> 4) * 4;
#pragma unroll
    for (int di = 0; di < 4; ++di) {
#pragma unroll
        for (int j = 0; j < 4; ++j) {
            int qr = qt0 + w * 16 + rb + j;
            O[base + (size_t)qr * Cm + di * 16 + lr] = (__bf16)(o_acc[di][j] * l_r[j]);
        }
    }
}

extern "C" void kernel_launch(void* const* d_in, const int* in_sizes, int n_in,
                              void* d_out, int out_size, void* d_ws, size_t ws_size,
                              hipStream_t stream) {
    const float* x  = (const float*)d_in[0];
    const float* wq = (const float*)d_in[1];
    const float* bq = (const float*)d_in[2];
    const float* wk = (const float*)d_in[3];
    const float* bk = (const float*)d_in[4];
    const float* wv = (const float*)d_in[5];
    const float* bv = (const float*)d_in[6];
    const float* wo = (const float*)d_in[7];
    const float* bo = (const float*)d_in[8];

    // B=4, T=2048, C=512 -> M = 8192 rows
    char* ws = (char*)d_ws;
    __bf16* xb    = (__bf16*)(ws);                                  // 8 MB
    __bf16* Qb    = (__bf16*)(ws + ((size_t)8 << 20));              // 8 MB
    __bf16* Kb    = (__bf16*)(ws + ((size_t)16 << 20));             // 8 MB
    __bf16* Vb    = (__bf16*)(ws + ((size_t)24 << 20));             // 8 MB
    __bf16* attnb = (__bf16*)(ws + ((size_t)32 << 20));             // 8 MB
    __bf16* wqb   = (__bf16*)(ws + ((size_t)40 << 20));             // 512 KB each
    __bf16* wkb   = (__bf16*)(ws + ((size_t)40 << 20) + ((size_t)512 << 10));
    __bf16* wvb   = (__bf16*)(ws + ((size_t)40 << 20) + ((size_t)1024 << 10));
    __bf16* wob   = (__bf16*)(ws + ((size_t)40 << 20) + ((size_t)1536 << 10));

    // conversions: x (4M elems), weights (256K each)
    cvt_f32_bf16<<<dim3(4096), dim3(256), 0, stream>>>(x, xb, 1048576);
    cvt_f32_bf16<<<dim3(256), dim3(256), 0, stream>>>(wq, wqb, 65536);
    cvt_f32_bf16<<<dim3(256), dim3(256), 0, stream>>>(wk, wkb, 65536);
    cvt_f32_bf16<<<dim3(256), dim3(256), 0, stream>>>(wv, wvb, 65536);
    cvt_f32_bf16<<<dim3(256), dim3(256), 0, stream>>>(wo, wob, 65536);

    // fused QKV projections (Q pre-scaled by 0.125)
    qkv_gemm<<<dim3(64, 4, 3), dim3(256), 0, stream>>>(xb, wqb, wkb, wvb,
                                                       bq, bk, bv, Qb, Kb, Vb);
    // flash attention
    attn_fwd<<<dim3(32, 8, 4), dim3(256), 0, stream>>>(Qb, Kb, Vb, attnb);
    // output projection -> f32 + bias
    out_gemm<<<dim3(64, 4), dim3(256), 0, stream>>>(attnb, wob, bo, (float*)d_out);
}

// Round 2
// 163.033 us; speedup vs baseline: 1.1262x; 1.1262x over previous
//
#include <hip/hip_runtime.h>

typedef __bf16 bf16x8 __attribute__((ext_vector_type(8)));
typedef __bf16 bf16x4 __attribute__((ext_vector_type(4)));
typedef float f32x4 __attribute__((ext_vector_type(4)));

#define MFMA_16x16x32(a, b, c) __builtin_amdgcn_mfma_f32_16x16x32_bf16((a), (b), (c), 0, 0, 0)

// hardware transpose-read: lane reads 4 bf16; given addr = 128B-block + (l&15)*8,
// delivers elem j = row j, col (l&15) of the 4x16 bf16 tile at that block.
#define TRD(dst, a, OFFSTR) \
    asm volatile("ds_read_b64_tr_b16 %0, %1 offset:" OFFSTR : "=v"(dst) : "v"(a))
#define LGKM0() do { asm volatile("s_waitcnt lgkmcnt(0)" ::: "memory"); \
                     __builtin_amdgcn_sched_barrier(0); } while (0)

union PU { unsigned long long r[2]; bf16x8 v; };

// XOR swizzle for row-major tiles with 128-byte rows (K tile only)
__device__ __forceinline__ int swz(int row, int colb) {
    return row * 128 + (colb ^ ((row & 7) << 4));
}

// ---------------- f32 -> bf16 conversion ----------------
__global__ __launch_bounds__(256) void cvt_f32_bf16(const float* __restrict__ in,
                                                    __bf16* __restrict__ out, int n4) {
    int i = blockIdx.x * 256 + threadIdx.x;
    if (i >= n4) return;
    float4 v = ((const float4*)in)[i];
    bf16x4 o;
    o[0] = (__bf16)v.x; o[1] = (__bf16)v.y; o[2] = (__bf16)v.z; o[3] = (__bf16)v.w;
    ((bf16x4*)out)[i] = o;
}

// ---- GEMM body: C[M][N] = (A[M][K] * Bw[N][K]^T + bias[N]) * scale ----
template <typename OT>
__device__ __forceinline__ void gemm_body(const __bf16* __restrict__ A,
                                          const __bf16* __restrict__ Bw,
                                          const float* __restrict__ bias,
                                          OT* __restrict__ C,
                                          int M, int N, int K, float scale) {
    const int m0 = blockIdx.x * 128;
    const int n0 = blockIdx.y * 128;
    const int tid = threadIdx.x;
    const int l = tid & 63, w = tid >> 6;
    const int wr = w >> 1, wc = w & 1;
    const int lr = l & 15;
    const int lkb = (l >> 4) << 4;

    __shared__ __bf16 As[128 * 64];
    __shared__ __bf16 Bs[128 * 64];
    char* AsC = (char*)As;
    char* BsC = (char*)Bs;

    f32x4 acc[4][4] = {};

    for (int k0 = 0; k0 < K; k0 += 64) {
        __syncthreads();
#pragma unroll
        for (int r = 0; r < 4; ++r) {
            int g = r * 256 + tid;
            int row = g >> 3, c = g & 7;
            int4 va = *(const int4*)(A + (size_t)(m0 + row) * K + k0 + c * 8);
            *(int4*)(AsC + swz(row, c * 16)) = va;
            int4 vb = *(const int4*)(Bw + (size_t)(n0 + row) * K + k0 + c * 8);
            *(int4*)(BsC + swz(row, c * 16)) = vb;
        }
        __syncthreads();
#pragma unroll
        for (int kk = 0; kk < 2; ++kk) {
            bf16x8 af[4], bfr[4];
#pragma unroll
            for (int mi = 0; mi < 4; ++mi)
                af[mi] = *(const bf16x8*)(AsC + swz(wr * 64 + mi * 16 + lr, kk * 64 + lkb));
#pragma unroll
            for (int ni = 0; ni < 4; ++ni)
                bfr[ni] = *(const bf16x8*)(BsC + swz(wc * 64 + ni * 16 + lr, kk * 64 + lkb));
#pragma unroll
            for (int mi = 0; mi < 4; ++mi)
#pragma unroll
                for (int ni = 0; ni < 4; ++ni)
                    acc[mi][ni] = MFMA_16x16x32(af[mi], bfr[ni], acc[mi][ni]);
        }
    }

    const int rb = (l >> 4) * 4;
#pragma unroll
    for (int mi = 0; mi < 4; ++mi) {
#pragma unroll
        for (int ni = 0; ni < 4; ++ni) {
            int gn = n0 + wc * 64 + ni * 16 + lr;
            int gm = m0 + wr * 64 + mi * 16 + rb;
            float bv = bias[gn];
#pragma unroll
            for (int j = 0; j < 4; ++j) {
                float v = (acc[mi][ni][j] + bv) * scale;
                C[(size_t)(gm + j) * N + gn] = (OT)v;
            }
        }
    }
}

__global__ __launch_bounds__(256) void qkv_gemm(const __bf16* __restrict__ X,
                                                const __bf16* __restrict__ Wq,
                                                const __bf16* __restrict__ Wk,
                                                const __bf16* __restrict__ Wv,
                                                const float* __restrict__ bq,
                                                const float* __restrict__ bk,
                                                const float* __restrict__ bv,
                                                __bf16* __restrict__ Qo,
                                                __bf16* __restrict__ Ko,
                                                __bf16* __restrict__ Vo) {
    int z = blockIdx.z;
    const __bf16* W = (z == 0) ? Wq : (z == 1) ? Wk : Wv;
    const float* bb = (z == 0) ? bq : (z == 1) ? bk : bv;
    __bf16* O = (z == 0) ? Qo : (z == 1) ? Ko : Vo;
    gemm_body<__bf16>(X, W, bb, O, 8192, 512, 512, (z == 0) ? 0.125f : 1.0f);
}

__global__ __launch_bounds__(256) void out_gemm(const __bf16* __restrict__ A,
                                                const __bf16* __restrict__ W,
                                                const float* __restrict__ bias,
                                                float* __restrict__ C) {
    gemm_body<float>(A, W, bias, C, 8192, 512, 512, 1.0f);
}

// ---------------- flash attention forward ----------------
// grid (T/128, H, B), 256 thr = 4 waves; wave w owns 32 q rows (2 m-frags).
// K: swizzled row-major dbuf. V: 4x16-subtiled dbuf (tr-read). P^T per wave.
__global__ __launch_bounds__(256, 2) void attn_fwd(const __bf16* __restrict__ Q,
                                                   const __bf16* __restrict__ K,
                                                   const __bf16* __restrict__ V,
                                                   __bf16* __restrict__ O) {
    const int T = 2048, Cm = 512;
    const int qt0 = blockIdx.x * 128;
    const int h = blockIdx.y, b = blockIdx.z;
    const int tid = threadIdx.x;
    const int l = tid & 63, w = tid >> 6;
    const int lr = l & 15, g4 = l >> 4, rb = g4 * 4;
    const size_t base = ((size_t)b * T) * Cm + h * 64;

    // 0..16K: K dbuf (2x8K swizzled [64][64]); 16K..32K: V dbuf (2x8K subtiled
    // [k/4][d/16][4][16]); 32K..48K: P^T, 4KB/wave ([mi][k/4][4][q16])
    __shared__ __align__(16) char smem[49152];
    const unsigned s0 = (unsigned)(uintptr_t)&smem[0];

    // staging: thread covers (row = tid>>3 [+32], d0 = (tid&7)*8), 16B each
    const int grow = tid >> 3;
    const int gcolb = (tid & 7) * 16;  // byte column
    const __bf16* kgp = K + base + (size_t)grow * Cm + (tid & 7) * 8;
    const __bf16* vgp = V + base + (size_t)grow * Cm + (tid & 7) * 8;
    const int kw0 = grow * 128 + (gcolb ^ ((grow & 7) << 4));
    const int vw0 = ((grow >> 2) * 4 + (gcolb >> 5)) * 128 + (grow & 3) * 32 + (gcolb & 31);

    // Q fragments in registers: qa[mi][kk]
    bf16x8 qa[2][2];
#pragma unroll
    for (int mi = 0; mi < 2; ++mi)
#pragma unroll
        for (int kk = 0; kk < 2; ++kk)
            qa[mi][kk] = *(const bf16x8*)(Q + base +
                (size_t)(qt0 + w * 32 + mi * 16 + lr) * Cm + g4 * 8 + kk * 32);

    f32x4 o_acc[2][4] = {};
    float m_r[2][4], l_r[2][4];
#pragma unroll
    for (int mi = 0; mi < 2; ++mi)
#pragma unroll
        for (int j = 0; j < 4; ++j) { m_r[mi][j] = -1e30f; l_r[mi][j] = 0.f; }

    // prologue: stage tile 0 into buffer 0
    {
        int4 k0 = *(const int4*)(kgp);
        int4 k1 = *(const int4*)(kgp + (size_t)32 * Cm);
        int4 v0 = *(const int4*)(vgp);
        int4 v1 = *(const int4*)(vgp + (size_t)32 * Cm);
        *(int4*)(smem + kw0) = k0;
        *(int4*)(smem + kw0 + 4096) = k1;
        *(int4*)(smem + 16384 + vw0) = v0;
        *(int4*)(smem + 16384 + vw0 + 4096) = v1;
    }
    __syncthreads();

    const unsigned prd = s0 + 32768 + w * 4096 + g4 * 256 + lr * 8;  // P tr-read base
    const int pw0 = 32768 + w * 4096 + (lr >> 2) * 128 + (lr & 3) * 32 + g4 * 8;

    int cur = 0;
    for (int kt = 0; kt < T; kt += 64, cur ^= 1) {
        // T14: issue next tile's global loads early (write to LDS after PV)
        int ktn = (kt + 64 < T) ? (kt + 64) : kt;
        int4 ks0 = *(const int4*)(kgp + (size_t)ktn * Cm);
        int4 ks1 = *(const int4*)(kgp + (size_t)(ktn + 32) * Cm);
        int4 vs0 = *(const int4*)(vgp + (size_t)ktn * Cm);
        int4 vs1 = *(const int4*)(vgp + (size_t)(ktn + 32) * Cm);

        // ---- S = Q K^T ----
        const char* kbase = smem + cur * 8192;
        f32x4 s[2][4] = {};
#pragma unroll
        for (int kk = 0; kk < 2; ++kk) {
            bf16x8 kb[4];
#pragma unroll
            for (int ni = 0; ni < 4; ++ni)
                kb[ni] = *(const bf16x8*)(kbase + swz(ni * 16 + lr, kk * 64 + g4 * 16));
#pragma unroll
            for (int ni = 0; ni < 4; ++ni)
#pragma unroll
                for (int mi = 0; mi < 2; ++mi)
                    s[mi][ni] = MFMA_16x16x32(qa[mi][kk], kb[ni], s[mi][ni]);
        }

        // ---- online softmax; write P^T (vectorized 8B rows) ----
#pragma unroll
        for (int mi = 0; mi < 2; ++mi) {
            float mx[4];
#pragma unroll
            for (int j = 0; j < 4; ++j)
                mx[j] = fmaxf(fmaxf(s[mi][0][j], s[mi][1][j]),
                              fmaxf(s[mi][2][j], s[mi][3][j]));
#pragma unroll
            for (int msk = 1; msk < 16; msk <<= 1)
#pragma unroll
                for (int j = 0; j < 4; ++j)
                    mx[j] = fmaxf(mx[j], __shfl_xor(mx[j], msk));
            float al[4], rs[4];
#pragma unroll
            for (int j = 0; j < 4; ++j) {
                float mn = fmaxf(m_r[mi][j], mx[j]);
                al[j] = __expf(m_r[mi][j] - mn);
                m_r[mi][j] = mn;
                rs[j] = 0.f;
            }
#pragma unroll
            for (int ni = 0; ni < 4; ++ni) {
                bf16x4 pb;
#pragma unroll
                for (int j = 0; j < 4; ++j) {
                    float pv = __expf(s[mi][ni][j] - m_r[mi][j]);
                    pb[j] = (__bf16)pv;
                    rs[j] += (float)pb[j];
                }
                *(bf16x4*)(smem + pw0 + mi * 2048 + ni * 512) = pb;
            }
#pragma unroll
            for (int msk = 1; msk < 16; msk <<= 1)
#pragma unroll
                for (int j = 0; j < 4; ++j)
                    rs[j] += __shfl_xor(rs[j], msk);
#pragma unroll
            for (int j = 0; j < 4; ++j)
                l_r[mi][j] = l_r[mi][j] * al[j] + rs[j];
#pragma unroll
            for (int di = 0; di < 4; ++di)
#pragma unroll
                for (int j = 0; j < 4; ++j)
                    o_acc[mi][di][j] *= al[j];
        }
        LGKM0();  // P^T writes visible to this wave's tr-reads

        // ---- O += P V (tr-reads for both P^T and subtiled V) ----
        const unsigned vrd = s0 + 16384 + cur * 8192 + g4 * 1024 + lr * 8;
#pragma unroll
        for (int kk = 0; kk < 2; ++kk) {
            PU pa[2], vb[4];
            TRD(pa[0].r[0], prd + kk * 1024, "0");
            TRD(pa[0].r[1], prd + kk * 1024, "128");
            TRD(pa[1].r[0], prd + kk * 1024 + 2048, "0");
            TRD(pa[1].r[1], prd + kk * 1024 + 2048, "128");
#pragma unroll
            for (int di = 0; di < 4; ++di) {
                TRD(vb[di].r[0], vrd + kk * 4096 + di * 128, "0");
                TRD(vb[di].r[1], vrd + kk * 4096 + di * 128, "512");
            }
            LGKM0();
#pragma unroll
            for (int di = 0; di < 4; ++di)
#pragma unroll
                for (int mi = 0; mi < 2; ++mi)
                    o_acc[mi][di] = MFMA_16x16x32(pa[mi].v, vb[di].v, o_acc[mi][di]);
        }

        // ---- write staged regs into the other buffer; single barrier ----
        {
            char* kd = smem + (cur ^ 1) * 8192;
            char* vd = smem + 16384 + (cur ^ 1) * 8192;
            *(int4*)(kd + kw0) = ks0;
            *(int4*)(kd + kw0 + 4096) = ks1;
            *(int4*)(vd + vw0) = vs0;
            *(int4*)(vd + vw0 + 4096) = vs1;
        }
        __syncthreads();
    }

    // epilogue
#pragma unroll
    for (int mi = 0; mi < 2; ++mi) {
        float inv[4];
#pragma unroll
        for (int j = 0; j < 4; ++j) inv[j] = 1.f / l_r[mi][j];
#pragma unroll
        for (int di = 0; di < 4; ++di)
#pragma unroll
            for (int j = 0; j < 4; ++j) {
                int qr = qt0 + w * 32 + mi * 16 + rb + j;
                O[base + (size_t)qr * Cm + di * 16 + lr] = (__bf16)(o_acc[mi][di][j] * inv[j]);
            }
    }
}

extern "C" void kernel_launch(void* const* d_in, const int* in_sizes, int n_in,
                              void* d_out, int out_size, void* d_ws, size_t ws_size,
                              hipStream_t stream) {
    const float* x  = (const float*)d_in[0];
    const float* wq = (const float*)d_in[1];
    const float* bq = (const float*)d_in[2];
    const float* wk = (const float*)d_in[3];
    const float* bk = (const float*)d_in[4];
    const float* wv = (const float*)d_in[5];
    const float* bv = (const float*)d_in[6];
    const float* wo = (const float*)d_in[7];
    const float* bo = (const float*)d_in[8];

    char* ws = (char*)d_ws;
    __bf16* xb    = (__bf16*)(ws);
    __bf16* Qb    = (__bf16*)(ws + ((size_t)8 << 20));
    __bf16* Kb    = (__bf16*)(ws + ((size_t)16 << 20));
    __bf16* Vb    = (__bf16*)(ws + ((size_t)24 << 20));
    __bf16* attnb = (__bf16*)(ws + ((size_t)32 << 20));
    __bf16* wqb   = (__bf16*)(ws + ((size_t)40 << 20));
    __bf16* wkb   = (__bf16*)(ws + ((size_t)40 << 20) + ((size_t)512 << 10));
    __bf16* wvb   = (__bf16*)(ws + ((size_t)40 << 20) + ((size_t)1024 << 10));
    __bf16* wob   = (__bf16*)(ws + ((size_t)40 << 20) + ((size_t)1536 << 10));

    cvt_f32_bf16<<<dim3(4096), dim3(256), 0, stream>>>(x, xb, 1048576);
    cvt_f32_bf16<<<dim3(256), dim3(256), 0, stream>>>(wq, wqb, 65536);
    cvt_f32_bf16<<<dim3(256), dim3(256), 0, stream>>>(wk, wkb, 65536);
    cvt_f32_bf16<<<dim3(256), dim3(256), 0, stream>>>(wv, wvb, 65536);
    cvt_f32_bf16<<<dim3(256), dim3(256), 0, stream>>>(wo, wob, 65536);

    qkv_gemm<<<dim3(64, 4, 3), dim3(256), 0, stream>>>(xb, wqb, wkb, wvb,
                                                       bq, bk, bv, Qb, Kb, Vb);
    attn_fwd<<<dim3(16, 8, 4), dim3(256), 0, stream>>>(Qb, Kb, Vb, attnb);
    out_gemm<<<dim3(64, 4), dim3(256), 0, stream>>>(attnb, wob, bo, (float*)d_out);
}

// Round 3
// 161.520 us; speedup vs baseline: 1.1367x; 1.0094x over previous
//
#include <hip/hip_runtime.h>

typedef __bf16 bf16x8 __attribute__((ext_vector_type(8)));
typedef __bf16 bf16x4 __attribute__((ext_vector_type(4)));
typedef float f32x4 __attribute__((ext_vector_type(4)));

#define MFMA_16x16x32(a, b, c) __builtin_amdgcn_mfma_f32_16x16x32_bf16((a), (b), (c), 0, 0, 0)

// hardware transpose-read: 16-lane group reads one 128B block; lane gets
// column (l&15), rows j=0..3 of the 4x16 row-major bf16 tile at that block.
#define TRD(dst, a, OFFSTR) \
    asm volatile("ds_read_b64_tr_b16 %0, %1 offset:" OFFSTR : "=v"(dst) : "v"(a))
#define WAIT_LGKM(NSTR) do { \
    asm volatile("s_waitcnt lgkmcnt(" NSTR ")" ::: "memory"); \
    __builtin_amdgcn_sched_barrier(0); } while (0)

union PU { unsigned long long r[2]; bf16x8 v; };

// XOR swizzle for row-major tiles with 128-byte rows
__device__ __forceinline__ int swz(int row, int colb) {
    return row * 128 + (colb ^ ((row & 7) << 4));
}

// ---------------- f32 -> bf16 conversion ----------------
__global__ __launch_bounds__(256) void cvt_f32_bf16(const float* __restrict__ in,
                                                    __bf16* __restrict__ out, int n4) {
    int i = blockIdx.x * 256 + threadIdx.x;
    if (i >= n4) return;
    float4 v = ((const float4*)in)[i];
    bf16x4 o;
    o[0] = (__bf16)v.x; o[1] = (__bf16)v.y; o[2] = (__bf16)v.z; o[3] = (__bf16)v.w;
    ((bf16x4*)out)[i] = o;
}

// ---- GEMM body: C[M][N] = (A[M][K] * Bw[N][K]^T + bias[N]) * scale ----
template <typename OT>
__device__ __forceinline__ void gemm_body(const __bf16* __restrict__ A,
                                          const __bf16* __restrict__ Bw,
                                          const float* __restrict__ bias,
                                          OT* __restrict__ C,
                                          int M, int N, int K, float scale) {
    const int m0 = blockIdx.x * 128;
    const int n0 = blockIdx.y * 128;
    const int tid = threadIdx.x;
    const int l = tid & 63, w = tid >> 6;
    const int wr = w >> 1, wc = w & 1;
    const int lr = l & 15;
    const int lkb = (l >> 4) << 4;

    __shared__ __bf16 As[128 * 64];
    __shared__ __bf16 Bs[128 * 64];
    char* AsC = (char*)As;
    char* BsC = (char*)Bs;

    f32x4 acc[4][4] = {};

    for (int k0 = 0; k0 < K; k0 += 64) {
        __syncthreads();
#pragma unroll
        for (int r = 0; r < 4; ++r) {
            int g = r * 256 + tid;
            int row = g >> 3, c = g & 7;
            int4 va = *(const int4*)(A + (size_t)(m0 + row) * K + k0 + c * 8);
            *(int4*)(AsC + swz(row, c * 16)) = va;
            int4 vb = *(const int4*)(Bw + (size_t)(n0 + row) * K + k0 + c * 8);
            *(int4*)(BsC + swz(row, c * 16)) = vb;
        }
        __syncthreads();
#pragma unroll
        for (int kk = 0; kk < 2; ++kk) {
            bf16x8 af[4], bfr[4];
#pragma unroll
            for (int mi = 0; mi < 4; ++mi)
                af[mi] = *(const bf16x8*)(AsC + swz(wr * 64 + mi * 16 + lr, kk * 64 + lkb));
#pragma unroll
            for (int ni = 0; ni < 4; ++ni)
                bfr[ni] = *(const bf16x8*)(BsC + swz(wc * 64 + ni * 16 + lr, kk * 64 + lkb));
#pragma unroll
            for (int mi = 0; mi < 4; ++mi)
#pragma unroll
                for (int ni = 0; ni < 4; ++ni)
                    acc[mi][ni] = MFMA_16x16x32(af[mi], bfr[ni], acc[mi][ni]);
        }
    }

    const int rb = (l >> 4) * 4;
#pragma unroll
    for (int mi = 0; mi < 4; ++mi) {
#pragma unroll
        for (int ni = 0; ni < 4; ++ni) {
            int gn = n0 + wc * 64 + ni * 16 + lr;
            int gm = m0 + wr * 64 + mi * 16 + rb;
            float bv = bias[gn];
#pragma unroll
            for (int j = 0; j < 4; ++j) {
                float v = (acc[mi][ni][j] + bv) * scale;
                C[(size_t)(gm + j) * N + gn] = (OT)v;
            }
        }
    }
}

__global__ __launch_bounds__(256) void qkv_gemm(const __bf16* __restrict__ X,
                                                const __bf16* __restrict__ Wq,
                                                const __bf16* __restrict__ Wk,
                                                const __bf16* __restrict__ Wv,
                                                const float* __restrict__ bq,
                                                const float* __restrict__ bk,
                                                const float* __restrict__ bv,
                                                __bf16* __restrict__ Qo,
                                                __bf16* __restrict__ Ko,
                                                __bf16* __restrict__ Vo) {
    int z = blockIdx.z;
    const __bf16* W = (z == 0) ? Wq : (z == 1) ? Wk : Wv;
    const float* bb = (z == 0) ? bq : (z == 1) ? bk : bv;
    __bf16* O = (z == 0) ? Qo : (z == 1) ? Ko : Vo;
    gemm_body<__bf16>(X, W, bb, O, 8192, 512, 512, (z == 0) ? 0.125f : 1.0f);
}

__global__ __launch_bounds__(256) void out_gemm(const __bf16* __restrict__ A,
                                                const __bf16* __restrict__ W,
                                                const float* __restrict__ bias,
                                                float* __restrict__ C) {
    gemm_body<float>(A, W, bias, C, 8192, 512, 512, 1.0f);
}

// ---------------- flash attention forward ----------------
// grid (T/64, H, B) = 1024 blocks (4/CU), 128 thr = 2 waves; wave owns 32 q rows.
// K: swizzled row-major dbuf. V: s21 [32][16]-subtiled dbuf (k-blocks at 128B).
__global__ __launch_bounds__(128, 2) void attn_fwd(const __bf16* __restrict__ Q,
                                                   const __bf16* __restrict__ K,
                                                   const __bf16* __restrict__ V,
                                                   __bf16* __restrict__ O) {
    const int T = 2048, Cm = 512;
    const int qt0 = blockIdx.x * 64;
    const int h = blockIdx.y, b = blockIdx.z;
    const int tid = threadIdx.x;           // 0..127
    const int l = tid & 63, w = tid >> 6;  // 2 waves
    const int lr = l & 15, g4 = l >> 4, rb = g4 * 4;
    const size_t base = ((size_t)b * T) * Cm + h * 64;

    // [0,16K): K dbuf (2x8K swizzled [64][64]); [16K,32K): V dbuf (2x8K s21
    // subtiled); [32K,40K): P^T per wave (4KB: [mi][k/4][4][q16])
    __shared__ __align__(16) char smem[40960];
    const unsigned s0 = (unsigned)(uintptr_t)&smem[0];

    // staging: 128 threads x 16B x 4 passes per tile (rows grow+16p)
    const int grow = tid >> 3;             // 0..15
    const int gc8 = (tid & 7) * 8;         // element column (d)
    const __bf16* kgp = K + base + (size_t)grow * Cm + gc8;
    const __bf16* vgp = V + base + (size_t)grow * Cm + gc8;
    int kwo[4], vwo[4];
#pragma unroll
    for (int p = 0; p < 4; ++p) {
        int r = grow + 16 * p;
        kwo[p] = swz(r, gc8 * 2);
        // s21 layout: subtile (k>>5)*4+(d>>4) of 1KB, then contiguous 128B k-blocks
        vwo[p] = ((r >> 5) * 4 + (gc8 >> 4)) * 1024 + ((r >> 2) & 7) * 128 +
                 (r & 3) * 32 + (gc8 & 15) * 2;
    }

    // Q fragments in registers: qa[mi][kk], rows qt0 + w*32 + mi*16 + lr
    bf16x8 qa[2][2];
#pragma unroll
    for (int mi = 0; mi < 2; ++mi)
#pragma unroll
        for (int kk = 0; kk < 2; ++kk)
            qa[mi][kk] = *(const bf16x8*)(Q + base +
                (size_t)(qt0 + w * 32 + mi * 16 + lr) * Cm + g4 * 8 + kk * 32);

    f32x4 o_acc[2][4] = {};
    float m_r[2][4], l_r[2][4];
#pragma unroll
    for (int mi = 0; mi < 2; ++mi)
#pragma unroll
        for (int j = 0; j < 4; ++j) { m_r[mi][j] = -1e30f; l_r[mi][j] = 0.f; }

    // prologue: stage tile 0 into buffer 0
#pragma unroll
    for (int p = 0; p < 4; ++p) {
        int4 kv = *(const int4*)(kgp + (size_t)(16 * p) * Cm);
        int4 vv = *(const int4*)(vgp + (size_t)(16 * p) * Cm);
        *(int4*)(smem + kwo[p]) = kv;
        *(int4*)(smem + 16384 + vwo[p]) = vv;
    }
    __syncthreads();

    const unsigned prd = s0 + 32768 + w * 4096 + g4 * 256 + lr * 8;
    const int pw0 = 32768 + w * 4096 + (lr >> 2) * 128 + (lr & 3) * 32 + g4 * 8;

    int cur = 0;
    for (int kt = 0; kt < T; kt += 64, cur ^= 1) {
        // T14: issue next tile's global loads early, LDS-write after PV
        int ktn = (kt + 64 < T) ? (kt + 64) : kt;
        int4 ks[4], vs[4];
#pragma unroll
        for (int p = 0; p < 4; ++p) {
            ks[p] = *(const int4*)(kgp + (size_t)(ktn + 16 * p) * Cm);
            vs[p] = *(const int4*)(vgp + (size_t)(ktn + 16 * p) * Cm);
        }

        // ---- S = Q K^T ----
        const char* kbase = smem + cur * 8192;
        f32x4 s[2][4] = {};
#pragma unroll
        for (int kk = 0; kk < 2; ++kk) {
            bf16x8 kb[4];
#pragma unroll
            for (int ni = 0; ni < 4; ++ni)
                kb[ni] = *(const bf16x8*)(kbase + swz(ni * 16 + lr, kk * 64 + g4 * 16));
            __builtin_amdgcn_s_setprio(1);
#pragma unroll
            for (int ni = 0; ni < 4; ++ni)
#pragma unroll
                for (int mi = 0; mi < 2; ++mi)
                    s[mi][ni] = MFMA_16x16x32(qa[mi][kk], kb[ni], s[mi][ni]);
            __builtin_amdgcn_s_setprio(0);
        }

        // ---- online softmax with defer-max (T13) ----
        float mx[2][4];
#pragma unroll
        for (int mi = 0; mi < 2; ++mi)
#pragma unroll
            for (int j = 0; j < 4; ++j)
                mx[mi][j] = fmaxf(fmaxf(s[mi][0][j], s[mi][1][j]),
                                  fmaxf(s[mi][2][j], s[mi][3][j]));
#pragma unroll
        for (int msk = 1; msk < 16; msk <<= 1)
#pragma unroll
            for (int mi = 0; mi < 2; ++mi)
#pragma unroll
                for (int j = 0; j < 4; ++j)
                    mx[mi][j] = fmaxf(mx[mi][j], __shfl_xor(mx[mi][j], msk));

        float dmax = -1e30f;
#pragma unroll
        for (int mi = 0; mi < 2; ++mi)
#pragma unroll
            for (int j = 0; j < 4; ++j)
                dmax = fmaxf(dmax, mx[mi][j] - m_r[mi][j]);

        float al[2][4];
#pragma unroll
        for (int mi = 0; mi < 2; ++mi)
#pragma unroll
            for (int j = 0; j < 4; ++j) al[mi][j] = 1.0f;

        if (!__all(dmax <= 8.0f)) {  // full rescale path (wave-uniform)
#pragma unroll
            for (int mi = 0; mi < 2; ++mi)
#pragma unroll
                for (int j = 0; j < 4; ++j) {
                    float mn = fmaxf(m_r[mi][j], mx[mi][j]);
                    al[mi][j] = __expf(m_r[mi][j] - mn);
                    m_r[mi][j] = mn;
                }
#pragma unroll
            for (int mi = 0; mi < 2; ++mi)
#pragma unroll
                for (int di = 0; di < 4; ++di)
#pragma unroll
                    for (int j = 0; j < 4; ++j)
                        o_acc[mi][di][j] *= al[mi][j];
        }

        // P = exp(s - m_r), write P^T (8B rows), accumulate row sums
#pragma unroll
        for (int mi = 0; mi < 2; ++mi) {
            float rs[4] = {0.f, 0.f, 0.f, 0.f};
#pragma unroll
            for (int ni = 0; ni < 4; ++ni) {
                bf16x4 pb;
#pragma unroll
                for (int j = 0; j < 4; ++j) {
                    float pv = __expf(s[mi][ni][j] - m_r[mi][j]);
                    pb[j] = (__bf16)pv;
                    rs[j] += (float)pb[j];
                }
                *(bf16x4*)(smem + pw0 + mi * 2048 + ni * 512) = pb;
            }
#pragma unroll
            for (int msk = 1; msk < 16; msk <<= 1)
#pragma unroll
                for (int j = 0; j < 4; ++j)
                    rs[j] += __shfl_xor(rs[j], msk);
#pragma unroll
            for (int j = 0; j < 4; ++j)
                l_r[mi][j] = l_r[mi][j] * al[mi][j] + rs[j];
        }

        // ---- O += P V: batch all tr-reads, counted waits ----
        asm volatile("" ::: "memory");  // keep P writes above the tr-reads
        const unsigned vrd = s0 + 16384 + cur * 8192 + g4 * 256 + lr * 8;
        PU pa[2][2], vb[2][4];
#pragma unroll
        for (int kk = 0; kk < 2; ++kk) {
            TRD(pa[kk][0].r[0], prd + kk * 1024, "0");
            TRD(pa[kk][0].r[1], prd + kk * 1024, "128");
            TRD(pa[kk][1].r[0], prd + kk * 1024 + 2048, "0");
            TRD(pa[kk][1].r[1], prd + kk * 1024 + 2048, "128");
#pragma unroll
            for (int di = 0; di < 4; ++di) {
                TRD(vb[kk][di].r[0], vrd + kk * 4096 + di * 1024, "0");
                TRD(vb[kk][di].r[1], vrd + kk * 4096 + di * 1024, "128");
            }
        }
        WAIT_LGKM("12");  // P writes + kk=0 frags complete
        __builtin_amdgcn_s_setprio(1);
#pragma unroll
        for (int di = 0; di < 4; ++di)
#pragma unroll
            for (int mi = 0; mi < 2; ++mi)
                o_acc[mi][di] = MFMA_16x16x32(pa[0][mi].v, vb[0][di].v, o_acc[mi][di]);
        __builtin_amdgcn_s_setprio(0);
        WAIT_LGKM("0");
        __builtin_amdgcn_s_setprio(1);
#pragma unroll
        for (int di = 0; di < 4; ++di)
#pragma unroll
            for (int mi = 0; mi < 2; ++mi)
                o_acc[mi][di] = MFMA_16x16x32(pa[1][mi].v, vb[1][di].v, o_acc[mi][di]);
        __builtin_amdgcn_s_setprio(0);

        // ---- write staged regs into the other buffer; single barrier ----
        {
            char* kd = smem + ((cur ^ 1) * 8192);
            char* vd = smem + 16384 + ((cur ^ 1) * 8192);
#pragma unroll
            for (int p = 0; p < 4; ++p) {
                *(int4*)(kd + kwo[p]) = ks[p];
                *(int4*)(vd + vwo[p]) = vs[p];
            }
        }
        __syncthreads();
    }

    // epilogue
#pragma unroll
    for (int mi = 0; mi < 2; ++mi) {
        float inv[4];
#pragma unroll
        for (int j = 0; j < 4; ++j) inv[j] = 1.f / l_r[mi][j];
#pragma unroll
        for (int di = 0; di < 4; ++di)
#pragma unroll
            for (int j = 0; j < 4; ++j) {
                int qr = qt0 + w * 32 + mi * 16 + rb + j;
                O[base + (size_t)qr * Cm + di * 16 + lr] = (__bf16)(o_acc[mi][di][j] * inv[j]);
            }
    }
}

extern "C" void kernel_launch(void* const* d_in, const int* in_sizes, int n_in,
                              void* d_out, int out_size, void* d_ws, size_t ws_size,
                              hipStream_t stream) {
    const float* x  = (const float*)d_in[0];
    const float* wq = (const float*)d_in[1];
    const float* bq = (const float*)d_in[2];
    const float* wk = (const float*)d_in[3];
    const float* bk = (const float*)d_in[4];
    const float* wv = (const float*)d_in[5];
    const float* bv = (const float*)d_in[6];
    const float* wo = (const float*)d_in[7];
    const float* bo = (const float*)d_in[8];

    char* ws = (char*)d_ws;
    __bf16* xb    = (__bf16*)(ws);
    __bf16* Qb    = (__bf16*)(ws + ((size_t)8 << 20));
    __bf16* Kb    = (__bf16*)(ws + ((size_t)16 << 20));
    __bf16* Vb    = (__bf16*)(ws + ((size_t)24 << 20));
    __bf16* attnb = (__bf16*)(ws + ((size_t)32 << 20));
    __bf16* wqb   = (__bf16*)(ws + ((size_t)40 << 20));
    __bf16* wkb   = (__bf16*)(ws + ((size_t)40 << 20) + ((size_t)512 << 10));
    __bf16* wvb   = (__bf16*)(ws + ((size_t)40 << 20) + ((size_t)1024 << 10));
    __bf16* wob   = (__bf16*)(ws + ((size_t)40 << 20) + ((size_t)1536 << 10));

    cvt_f32_bf16<<<dim3(4096), dim3(256), 0, stream>>>(x, xb, 1048576);
    cvt_f32_bf16<<<dim3(256), dim3(256), 0, stream>>>(wq, wqb, 65536);
    cvt_f32_bf16<<<dim3(256), dim3(256), 0, stream>>>(wk, wkb, 65536);
    cvt_f32_bf16<<<dim3(256), dim3(256), 0, stream>>>(wv, wvb, 65536);
    cvt_f32_bf16<<<dim3(256), dim3(256), 0, stream>>>(wo, wob, 65536);

    qkv_gemm<<<dim3(64, 4, 3), dim3(256), 0, stream>>>(xb, wqb, wkb, wvb,
                                                       bq, bk, bv, Qb, Kb, Vb);
    attn_fwd<<<dim3(32, 8, 4), dim3(128), 0, stream>>>(Qb, Kb, Vb, attnb);
    out_gemm<<<dim3(64, 4), dim3(256), 0, stream>>>(attnb, wob, bo, (float*)d_out);
}

// Round 4
// 133.679 us; speedup vs baseline: 1.3735x; 1.2083x over previous
//
#include <hip/hip_runtime.h>

typedef __bf16 bf16x8 __attribute__((ext_vector_type(8)));
typedef __bf16 bf16x4 __attribute__((ext_vector_type(4)));
typedef float f32x4 __attribute__((ext_vector_type(4)));
typedef float f32x16 __attribute__((ext_vector_type(16)));

#define MFMA_16x16x32(a, b, c) __builtin_amdgcn_mfma_f32_16x16x32_bf16((a), (b), (c), 0, 0, 0)
#define MFMA32(a, b, c) __builtin_amdgcn_mfma_f32_32x32x16_bf16((a), (b), (c), 0, 0, 0)

#define WAIT_LGKM0() do { \
    asm volatile("s_waitcnt lgkmcnt(0)" ::: "memory"); \
    __builtin_amdgcn_sched_barrier(0); } while (0)

// pack 2 f32 -> 2 bf16 (RNE) in one u32: low16 = lo, high16 = hi
__device__ __forceinline__ unsigned cvtpk(float lo, float hi) {
    unsigned r;
    asm("v_cvt_pk_bf16_f32 %0, %1, %2" : "=v"(r) : "v"(lo), "v"(hi));
    return r;
}
// swap: a.lanes[32:63] <-> b.lanes[0:31]
#define PSWAP(a, b) asm volatile("v_permlane32_swap_b32 %0, %1" : "+v"(a), "+v"(b))

union PB { unsigned u[4]; bf16x8 v; };

// XOR swizzle for row-major tiles with 128-byte rows
__device__ __forceinline__ int swz(int row, int colb) {
    return row * 128 + (colb ^ ((row & 7) << 4));
}

// ---------------- f32 -> bf16 conversion ----------------
__global__ __launch_bounds__(256) void cvt_f32_bf16(const float* __restrict__ in,
                                                    __bf16* __restrict__ out, int n4) {
    int i = blockIdx.x * 256 + threadIdx.x;
    if (i >= n4) return;
    float4 v = ((const float4*)in)[i];
    bf16x4 o;
    o[0] = (__bf16)v.x; o[1] = (__bf16)v.y; o[2] = (__bf16)v.z; o[3] = (__bf16)v.w;
    ((bf16x4*)out)[i] = o;
}

// ---- GEMM body: C[M][N] = (A[M][K] * Bw[N][K]^T + bias[N]) * scale ----
// VT=true: write C transposed per-batch as C_T[b][n][t] (for V^T), b = row>>11.
template <typename OT, bool VT>
__device__ __forceinline__ void gemm_body(const __bf16* __restrict__ A,
                                          const __bf16* __restrict__ Bw,
                                          const float* __restrict__ bias,
                                          OT* __restrict__ C,
                                          int M, int N, int K, float scale) {
    const int m0 = blockIdx.x * 128;
    const int n0 = blockIdx.y * 128;
    const int tid = threadIdx.x;
    const int l = tid & 63, w = tid >> 6;
    const int wr = w >> 1, wc = w & 1;
    const int lr = l & 15;
    const int lkb = (l >> 4) << 4;

    __shared__ __bf16 As[128 * 64];
    __shared__ __bf16 Bs[128 * 64];
    char* AsC = (char*)As;
    char* BsC = (char*)Bs;

    f32x4 acc[4][4] = {};

    for (int k0 = 0; k0 < K; k0 += 64) {
        __syncthreads();
#pragma unroll
        for (int r = 0; r < 4; ++r) {
            int g = r * 256 + tid;
            int row = g >> 3, c = g & 7;
            int4 va = *(const int4*)(A + (size_t)(m0 + row) * K + k0 + c * 8);
            *(int4*)(AsC + swz(row, c * 16)) = va;
            int4 vb = *(const int4*)(Bw + (size_t)(n0 + row) * K + k0 + c * 8);
            *(int4*)(BsC + swz(row, c * 16)) = vb;
        }
        __syncthreads();
#pragma unroll
        for (int kk = 0; kk < 2; ++kk) {
            bf16x8 af[4], bfr[4];
#pragma unroll
            for (int mi = 0; mi < 4; ++mi)
                af[mi] = *(const bf16x8*)(AsC + swz(wr * 64 + mi * 16 + lr, kk * 64 + lkb));
#pragma unroll
            for (int ni = 0; ni < 4; ++ni)
                bfr[ni] = *(const bf16x8*)(BsC + swz(wc * 64 + ni * 16 + lr, kk * 64 + lkb));
#pragma unroll
            for (int mi = 0; mi < 4; ++mi)
#pragma unroll
                for (int ni = 0; ni < 4; ++ni)
                    acc[mi][ni] = MFMA_16x16x32(af[mi], bfr[ni], acc[mi][ni]);
        }
    }

    const int rb = (l >> 4) * 4;
#pragma unroll
    for (int mi = 0; mi < 4; ++mi) {
#pragma unroll
        for (int ni = 0; ni < 4; ++ni) {
            int gn = n0 + wc * 64 + ni * 16 + lr;
            int gm = m0 + wr * 64 + mi * 16 + rb;
            float bv = bias[gn];
            if constexpr (VT) {
                bf16x4 o4;
#pragma unroll
                for (int j = 0; j < 4; ++j)
                    o4[j] = (__bf16)((acc[mi][ni][j] + bv) * scale);
                *(bf16x4*)((__bf16*)C + ((size_t)(gm >> 11) << 20) +
                           (size_t)gn * 2048 + (gm & 2047)) = o4;
            } else {
#pragma unroll
                for (int j = 0; j < 4; ++j) {
                    float v = (acc[mi][ni][j] + bv) * scale;
                    C[(size_t)(gm + j) * N + gn] = (OT)v;
                }
            }
        }
    }
}

__global__ __launch_bounds__(256) void qkv_gemm(const __bf16* __restrict__ X,
                                                const __bf16* __restrict__ Wq,
                                                const __bf16* __restrict__ Wk,
                                                const __bf16* __restrict__ Wv,
                                                const float* __restrict__ bq,
                                                const float* __restrict__ bk,
                                                const float* __restrict__ bv,
                                                __bf16* __restrict__ Qo,
                                                __bf16* __restrict__ Ko,
                                                __bf16* __restrict__ Vto) {
    int z = blockIdx.z;
    if (z == 0) {
        gemm_body<__bf16, false>(X, Wq, bq, Qo, 8192, 512, 512, 0.125f);
    } else if (z == 1) {
        gemm_body<__bf16, false>(X, Wk, bk, Ko, 8192, 512, 512, 1.0f);
    } else {
        gemm_body<__bf16, true>(X, Wv, bv, Vto, 8192, 512, 512, 1.0f);
    }
}

__global__ __launch_bounds__(256) void out_gemm(const __bf16* __restrict__ A,
                                                const __bf16* __restrict__ W,
                                                const float* __restrict__ bias,
                                                float* __restrict__ C) {
    gemm_body<float, false>(A, W, bias, C, 8192, 512, 512, 1.0f);
}

// ---------------- flash attention forward ----------------
// grid (T/64, H, B), 128 thr = 2 waves, wave owns 32 q-rows (one per lane pair).
// Swapped QK^T (32x32x16): S^T = mfma(K, Q) -> lane-local softmax, P stays in
// registers (cvt_pk + permlane32_swap -> PV A-frag). K and V^T staged in LDS,
// XOR-swizzled, double-buffered, plain ds_read_b128 fragments.
__global__ __launch_bounds__(128, 2) void attn_fwd(const __bf16* __restrict__ Q,
                                                   const __bf16* __restrict__ K,
                                                   const __bf16* __restrict__ Vt,
                                                   __bf16* __restrict__ O) {
    const int T = 2048, Cm = 512;
    const int qt0 = blockIdx.x * 64;
    const int h = blockIdx.y, b = blockIdx.z;
    const int tid = threadIdx.x;
    const int l = tid & 63, w = tid >> 6;
    const int q5 = l & 31, hi = l >> 5;
    const size_t rbase = ((size_t)b * T) * Cm + h * 64;                 // Q,K,O
    const size_t vtbase = ((size_t)b << 20) + (size_t)(h * 64) * 2048;  // Vt

    // [0,16K): K dbuf; [16K,32K): V^T dbuf; [32K,32K+256): al scratch
    __shared__ __align__(16) char smem[33024];

    // staging: 128 thr x 16B x 4 passes per 8KB tile (rows grow+16p)
    const int grow = tid >> 3;      // 0..15
    const int gc8 = (tid & 7) * 8;  // element col within 64
    const __bf16* kgp = K + rbase + (size_t)grow * Cm + gc8;
    const __bf16* vgp = Vt + vtbase + (size_t)grow * 2048 + gc8;
    int two[4];
#pragma unroll
    for (int p = 0; p < 4; ++p) two[p] = swz(grow + 16 * p, gc8 * 2);

    // Q fragments (B-operand): lane holds Q[q5][dc*16 + hi*8 + j]
    bf16x8 qf[4];
#pragma unroll
    for (int dc = 0; dc < 4; ++dc)
        qf[dc] = *(const bf16x8*)(Q + rbase +
            (size_t)(qt0 + w * 32 + q5) * Cm + dc * 16 + hi * 8);

    f32x16 oa[2] = {};
    float m_r = -1e30f, l_r = 0.f;

    // prologue: stage tile 0 into buffer 0
#pragma unroll
    for (int p = 0; p < 4; ++p) {
        int4 kv = *(const int4*)(kgp + (size_t)(16 * p) * Cm);
        int4 vv = *(const int4*)(vgp + (size_t)(16 * p) * 2048);
        *(int4*)(smem + two[p]) = kv;
        *(int4*)(smem + 16384 + two[p]) = vv;
    }
    __syncthreads();

    char* albase = smem + 32768 + w * 128;

    int cur = 0;
    for (int kt = 0; kt < T; kt += 64, cur ^= 1) {
        // T14: issue next tile's global loads early; LDS-write after PV
        int ktn = (kt + 64 < T) ? kt + 64 : kt;
        int4 ks[4], vs[4];
#pragma unroll
        for (int p = 0; p < 4; ++p) {
            ks[p] = *(const int4*)(kgp + (size_t)(ktn + 16 * p) * Cm);
            vs[p] = *(const int4*)(vgp + (size_t)(16 * p) * 2048 + ktn);
        }

        // ---- S^T = K Q^T : lane holds S[q=q5][k = kb*32 + (r&3)+8*(r>>2)+4*hi]
        const char* kb_ = smem + cur * 8192;
        f32x16 s0 = {}, s1 = {};
#pragma unroll
        for (int dc = 0; dc < 4; ++dc) {
            bf16x8 kf0 = *(const bf16x8*)(kb_ + swz(q5, dc * 32 + hi * 16));
            bf16x8 kf1 = *(const bf16x8*)(kb_ + swz(32 + q5, dc * 32 + hi * 16));
            __builtin_amdgcn_s_setprio(1);
            s0 = MFMA32(kf0, qf[dc], s0);
            s1 = MFMA32(kf1, qf[dc], s1);
            __builtin_amdgcn_s_setprio(0);
        }

        // ---- in-lane softmax ----
        float t[16];
#pragma unroll
        for (int r = 0; r < 16; ++r) t[r] = fmaxf(s0[r], s1[r]);
#pragma unroll
        for (int d = 8; d >= 1; d >>= 1)
#pragma unroll
            for (int r = 0; r < d; ++r) t[r] = fmaxf(t[r], t[r + d]);
        float pm = fmaxf(t[0], __shfl_xor(t[0], 32));

        if (__any(pm - m_r > 8.0f)) {  // defer-max: rescale only when needed
            float mn = fmaxf(m_r, pm);
            float alv = __expf(m_r - mn);
            m_r = mn;
            *(float*)(albase + q5 * 4) = alv;
            WAIT_LGKM0();
            f32x4 alr[4];
#pragma unroll
            for (int rg = 0; rg < 4; ++rg)
                alr[rg] = *(const f32x4*)(albase + hi * 16 + rg * 32);
#pragma unroll
            for (int r = 0; r < 16; ++r) {
                oa[0][r] *= alr[r >> 2][r & 3];
                oa[1][r] *= alr[r >> 2][r & 3];
            }
            l_r *= alv;
        }

        float rs0 = 0.f, rs1 = 0.f;
#pragma unroll
        for (int r = 0; r < 16; ++r) {
            float p0 = __expf(s0[r] - m_r);
            float p1 = __expf(s1[r] - m_r);
            s0[r] = p0; s1[r] = p1;
            rs0 += p0; rs1 += p1;
        }
        float rsum = rs0 + rs1;
        rsum += __shfl_xor(rsum, 32);
        l_r += rsum;

        // ---- P -> bf16 PV A-frags in registers (16 cvt_pk + 8 permlane) ----
        PB pf[4];
#pragma unroll
        for (int kb = 0; kb < 2; ++kb) {
#pragma unroll
            for (int cc = 0; cc < 2; ++cc) {
                int gA = 8 * cc, gB = 8 * cc + 4;  // element bases of groups
                float a0, a1, a2, a3, b0, b1, b2, b3;
                if (kb == 0) {
                    a0 = s0[gA]; a1 = s0[gA + 1]; a2 = s0[gA + 2]; a3 = s0[gA + 3];
                    b0 = s0[gB]; b1 = s0[gB + 1]; b2 = s0[gB + 2]; b3 = s0[gB + 3];
                } else {
                    a0 = s1[gA]; a1 = s1[gA + 1]; a2 = s1[gA + 2]; a3 = s1[gA + 3];
                    b0 = s1[gB]; b1 = s1[gB + 1]; b2 = s1[gB + 2]; b3 = s1[gB + 3];
                }
                unsigned w0A = cvtpk(a0, a1), w1A = cvtpk(a2, a3);
                unsigned w0B = cvtpk(b0, b1), w1B = cvtpk(b2, b3);
                PSWAP(w0A, w0B);  // w0A=frag word0, w0B=frag word2
                PSWAP(w1A, w1B);  // w1A=frag word1, w1B=frag word3
                int kc = 2 * kb + cc;
                pf[kc].u[0] = w0A; pf[kc].u[1] = w1A;
                pf[kc].u[2] = w0B; pf[kc].u[3] = w1B;
            }
        }

        // ---- O += P V : B-frags from V^T tile (row = d, col = k) ----
        const char* vb_ = smem + 16384 + cur * 8192;
#pragma unroll
        for (int kc = 0; kc < 4; ++kc) {
            bf16x8 vf0 = *(const bf16x8*)(vb_ + swz(q5, kc * 32 + hi * 16));
            bf16x8 vf1 = *(const bf16x8*)(vb_ + swz(32 + q5, kc * 32 + hi * 16));
            __builtin_amdgcn_s_setprio(1);
            oa[0] = MFMA32(pf[kc].v, vf0, oa[0]);
            oa[1] = MFMA32(pf[kc].v, vf1, oa[1]);
            __builtin_amdgcn_s_setprio(0);
        }

        // ---- write staged regs into the other buffer; single barrier ----
        {
            char* kd = smem + ((cur ^ 1) * 8192);
            char* vd = smem + 16384 + ((cur ^ 1) * 8192);
#pragma unroll
            for (int p = 0; p < 4; ++p) {
                *(int4*)(kd + two[p]) = ks[p];
                *(int4*)(vd + two[p]) = vs[p];
            }
        }
        __syncthreads();
    }

    // ---- epilogue: redistribute 1/l over the C-layout rows, store ----
    {
        float invl = 1.f / l_r;
        *(float*)(albase + q5 * 4) = invl;
        WAIT_LGKM0();
        f32x4 ivr[4];
#pragma unroll
        for (int rg = 0; rg < 4; ++rg)
            ivr[rg] = *(const f32x4*)(albase + hi * 16 + rg * 32);
#pragma unroll
        for (int rg = 0; rg < 4; ++rg)
#pragma unroll
            for (int c = 0; c < 4; ++c) {
                int qr = qt0 + w * 32 + 8 * rg + 4 * hi + c;
                float iv = ivr[rg][c];
                O[rbase + (size_t)qr * Cm + q5]      = (__bf16)(oa[0][4 * rg + c] * iv);
                O[rbase + (size_t)qr * Cm + 32 + q5] = (__bf16)(oa[1][4 * rg + c] * iv);
            }
    }
}

extern "C" void kernel_launch(void* const* d_in, const int* in_sizes, int n_in,
                              void* d_out, int out_size, void* d_ws, size_t ws_size,
                              hipStream_t stream) {
    const float* x  = (const float*)d_in[0];
    const float* wq = (const float*)d_in[1];
    const float* bq = (const float*)d_in[2];
    const float* wk = (const float*)d_in[3];
    const float* bk = (const float*)d_in[4];
    const float* wv = (const float*)d_in[5];
    const float* bv = (const float*)d_in[6];
    const float* wo = (const float*)d_in[7];
    const float* bo = (const float*)d_in[8];

    char* ws = (char*)d_ws;
    __bf16* xb    = (__bf16*)(ws);
    __bf16* Qb    = (__bf16*)(ws + ((size_t)8 << 20));
    __bf16* Kb    = (__bf16*)(ws + ((size_t)16 << 20));
    __bf16* Vtb   = (__bf16*)(ws + ((size_t)24 << 20));  // V^T [b][512][2048]
    __bf16* attnb = (__bf16*)(ws + ((size_t)32 << 20));
    __bf16* wqb   = (__bf16*)(ws + ((size_t)40 << 20));
    __bf16* wkb   = (__bf16*)(ws + ((size_t)40 << 20) + ((size_t)512 << 10));
    __bf16* wvb   = (__bf16*)(ws + ((size_t)40 << 20) + ((size_t)1024 << 10));
    __bf16* wob   = (__bf16*)(ws + ((size_t)40 << 20) + ((size_t)1536 << 10));

    cvt_f32_bf16<<<dim3(4096), dim3(256), 0, stream>>>(x, xb, 1048576);
    cvt_f32_bf16<<<dim3(256), dim3(256), 0, stream>>>(wq, wqb, 65536);
    cvt_f32_bf16<<<dim3(256), dim3(256), 0, stream>>>(wk, wkb, 65536);
    cvt_f32_bf16<<<dim3(256), dim3(256), 0, stream>>>(wv, wvb, 65536);
    cvt_f32_bf16<<<dim3(256), dim3(256), 0, stream>>>(wo, wob, 65536);

    qkv_gemm<<<dim3(64, 4, 3), dim3(256), 0, stream>>>(xb, wqb, wkb, wvb,
                                                       bq, bk, bv, Qb, Kb, Vtb);
    attn_fwd<<<dim3(32, 8, 4), dim3(128), 0, stream>>>(Qb, Kb, Vtb, attnb);
    out_gemm<<<dim3(64, 4), dim3(256), 0, stream>>>(attnb, wob, bo, (float*)d_out);
}